// Round 13
// baseline (57.016 us; speedup 1.0000x reference)
//
#include <hip/hip_runtime.h>

#define B 2
#define S 512
#define D 256
#define C2L 2.885390081777927f    // 2*log2(e)
#define LOG2E 1.4426950408889634f

// proj: Pt = (q @ W^T) * C2L.
//   EJ4[b][e>>2][i][e&3] = exp2(Pt)  (float4-over-e: score loads dwordx4, coalesced)
//   EN[b][i][e] = exp2(-Pt)          (row-major; consumed via SCALAR s_load in fused)
//   W2[e] = -2*vm[e]                 (scalar-load stream)
__global__ __launch_bounds__(256) void proj_kernel(const float* __restrict__ q,
                                                   const float* __restrict__ W,
                                                   const float* __restrict__ vm,
                                                   float* __restrict__ EJ4,
                                                   float* __restrict__ EN,
                                                   float* __restrict__ W2) {
    __shared__ float qlds[4 * D];
    const int t = threadIdx.x;
    const int b = blockIdx.x / (S / 4);
    const int i0 = (blockIdx.x % (S / 4)) * 4;
    if (blockIdx.x == 0) W2[t] = -2.f * vm[t];
    const float* qbase = q + (size_t)(b * S + i0) * D;
    for (int idx = t; idx < 4 * D; idx += 256) qlds[idx] = qbase[idx];
    __syncthreads();
    const float* wr = W + (size_t)t * D;
    float a0 = 0.f, a1 = 0.f, a2 = 0.f, a3 = 0.f;
#pragma unroll 4
    for (int d = 0; d < D; ++d) {
        float w = wr[d];
        a0 = fmaf(qlds[d], w, a0);
        a1 = fmaf(qlds[D + d], w, a1);
        a2 = fmaf(qlds[2 * D + d], w, a2);
        a3 = fmaf(qlds[3 * D + d], w, a3);
    }
    a0 *= C2L; a1 *= C2L; a2 *= C2L; a3 *= C2L;
    float* ejb = EJ4 + (((size_t)(b * 64 + (t >> 2))) * S + i0) * 4 + (t & 3);
    ejb[0]  = __builtin_amdgcn_exp2f(a0);
    ejb[4]  = __builtin_amdgcn_exp2f(a1);
    ejb[8]  = __builtin_amdgcn_exp2f(a2);
    ejb[12] = __builtin_amdgcn_exp2f(a3);
    EN[(size_t)(b * S + i0 + 0) * D + t] = __builtin_amdgcn_exp2f(-a0);
    EN[(size_t)(b * S + i0 + 1) * D + t] = __builtin_amdgcn_exp2f(-a1);
    EN[(size_t)(b * S + i0 + 2) * D + t] = __builtin_amdgcn_exp2f(-a2);
    EN[(size_t)(b * S + i0 + 3) * D + t] = __builtin_amdgcn_exp2f(-a3);
}

// DIAGNOSTIC build of r12's fused kernel: the score loop runs TWICE (pass B via
// asm-opaqued pointers, data-dependent on pass A so the passes cannot be CSE'd
// or overlapped). accR = (a+b)*0.5 is bit-exact vs r12. The dur delta vs r12
// measures the score phase's true cost; the doubled kernel surfaces in the
// rocprof top-5 with its own counters.
__global__ __launch_bounds__(512, 2) void fused2x_kernel(const float* __restrict__ EJ4,
                                                         const float* __restrict__ EN,
                                                         const float* __restrict__ W2,
                                                         const float* __restrict__ value,
                                                         float* __restrict__ att,
                                                         float* __restrict__ ctx) {
    __shared__ float a2s[S][2];          // normalized attention rows
    __shared__ float part[2][8][64][4];  // ctx partials
    __shared__ float redm[2][8], reds[2][8];

    const int t = threadIdx.x;
    const int b = blockIdx.x >> 8;           // S/2 = 256 blocks per batch
    const int i0 = (blockIdx.x & 255) * 2;

    const float4* ejp = (const float4*)EJ4 + (size_t)b * 64 * S + t;
    const float4* f0p = (const float4*)(EN + ((size_t)(b * S + i0)) * D);      // uniform
    const float4* f1p = (const float4*)(EN + ((size_t)(b * S + i0 + 1)) * D);  // uniform
    const float4* wp  = (const float4*)W2;                                     // uniform

    // ---- score pass A ----
    float acc0a = 0.f, acc1a = 0.f;
#pragma unroll 4
    for (int g = 0; g < 64; ++g) {
        float4 ev4 = ejp[(size_t)g * S];
        float4 f0 = f0p[g];
        float4 f1 = f1p[g];
        float4 wv = wp[g];
#pragma unroll
        for (int c = 0; c < 4; ++c) {
            const float ev = (c == 0) ? ev4.x : (c == 1) ? ev4.y
                           : (c == 2) ? ev4.z : ev4.w;
            const float fa = (c == 0) ? f0.x : (c == 1) ? f0.y
                           : (c == 2) ? f0.z : f0.w;
            const float fb = (c == 0) ? f1.x : (c == 1) ? f1.y
                           : (c == 2) ? f1.z : f1.w;
            const float w  = (c == 0) ? wv.x : (c == 1) ? wv.y
                           : (c == 2) ? wv.z : wv.w;
            float y0 = fmaf(ev, fa, 1.f);
            float y1 = fmaf(ev, fb, 1.f);
            float r  = __builtin_amdgcn_rcpf(y0 * y1);
            acc0a = fmaf(w * y1, r, acc0a);
            acc1a = fmaf(w * y0, r, acc1a);
        }
    }

    // ---- opaque zero offsets, data-dependent on pass A (forces order, kills CSE)
    unsigned zoff = 0;
    asm volatile("" : "+v"(zoff) : "v"(acc0a), "v"(acc1a));
    unsigned soff = 0;
    asm volatile("" : "+s"(soff) : "v"(acc0a));
    const float4* ejp2 = ejp + zoff;
    const float4* f0p2 = f0p + soff;
    const float4* f1p2 = f1p + soff;
    const float4* wp2  = wp + soff;

    // ---- score pass B (identical math, un-provably-same operands) ----
    float acc0b = 0.f, acc1b = 0.f;
#pragma unroll 4
    for (int g = 0; g < 64; ++g) {
        float4 ev4 = ejp2[(size_t)g * S];
        float4 f0 = f0p2[g];
        float4 f1 = f1p2[g];
        float4 wv = wp2[g];
#pragma unroll
        for (int c = 0; c < 4; ++c) {
            const float ev = (c == 0) ? ev4.x : (c == 1) ? ev4.y
                           : (c == 2) ? ev4.z : ev4.w;
            const float fa = (c == 0) ? f0.x : (c == 1) ? f0.y
                           : (c == 2) ? f0.z : f0.w;
            const float fb = (c == 0) ? f1.x : (c == 1) ? f1.y
                           : (c == 2) ? f1.z : f1.w;
            const float w  = (c == 0) ? wv.x : (c == 1) ? wv.y
                           : (c == 2) ? wv.z : wv.w;
            float y0 = fmaf(ev, fa, 1.f);
            float y1 = fmaf(ev, fb, 1.f);
            float r  = __builtin_amdgcn_rcpf(y0 * y1);
            acc0b = fmaf(w * y1, r, acc0b);
            acc1b = fmaf(w * y0, r, acc1b);
        }
    }

    float acc0 = (acc0a + acc0b) * 0.5f;   // bit-exact: x+x == 2x exactly
    float acc1 = (acc1a + acc1b) * 0.5f;

    // ---- softmax over j (one value per thread per row, 8 waves)
    const int lane = t & 63, wv8 = t >> 6;
    {
        float lm0 = acc0, lm1 = acc1;
#pragma unroll
        for (int off = 32; off; off >>= 1) {
            lm0 = fmaxf(lm0, __shfl_xor(lm0, off));
            lm1 = fmaxf(lm1, __shfl_xor(lm1, off));
        }
        if (lane == 0) { redm[0][wv8] = lm0; redm[1][wv8] = lm1; }
    }
    __syncthreads();
    float m0 = redm[0][0], m1 = redm[1][0];
#pragma unroll
    for (int w = 1; w < 8; ++w) {
        m0 = fmaxf(m0, redm[0][w]);
        m1 = fmaxf(m1, redm[1][w]);
    }
    float p0 = __builtin_amdgcn_exp2f((acc0 - m0) * LOG2E);
    float p1 = __builtin_amdgcn_exp2f((acc1 - m1) * LOG2E);
    {
        float ls0 = p0, ls1 = p1;
#pragma unroll
        for (int off = 32; off; off >>= 1) {
            ls0 += __shfl_xor(ls0, off);
            ls1 += __shfl_xor(ls1, off);
        }
        if (lane == 0) { reds[0][wv8] = ls0; reds[1][wv8] = ls1; }
    }
    __syncthreads();
    float s0 = 0.f, s1 = 0.f;
#pragma unroll
    for (int w = 0; w < 8; ++w) { s0 += reds[0][w]; s1 += reds[1][w]; }
    float a0 = p0 * __builtin_amdgcn_rcpf(s0);
    float a1 = p1 * __builtin_amdgcn_rcpf(s1);
    a2s[t][0] = a0;
    a2s[t][1] = a1;
    att[(size_t)(b * S + i0) * S + t] = a0;
    att[(size_t)(b * S + i0 + 1) * S + t] = a1;
    __syncthreads();

    // ---- context: thread -> (dq = t&63, js = t>>6); value read once per block
    {
        const int dq = t & 63, js = t >> 6;
        float4 c0 = {}, c1 = {};
        const float* vb = value + (size_t)b * S * D + (size_t)dq * 4;
#pragma unroll 4
        for (int jj = 0; jj < 64; ++jj) {
            int jx = js * 64 + jj;
            float4 v = *(const float4*)(vb + (size_t)jx * D);
            float w0 = a2s[jx][0], w1 = a2s[jx][1];
            c0.x = fmaf(w0, v.x, c0.x); c0.y = fmaf(w0, v.y, c0.y);
            c0.z = fmaf(w0, v.z, c0.z); c0.w = fmaf(w0, v.w, c0.w);
            c1.x = fmaf(w1, v.x, c1.x); c1.y = fmaf(w1, v.y, c1.y);
            c1.z = fmaf(w1, v.z, c1.z); c1.w = fmaf(w1, v.w, c1.w);
        }
        *(float4*)&part[0][js][dq][0] = c0;
        *(float4*)&part[1][js][dq][0] = c1;
    }
    __syncthreads();
    if (t < 128) {
        const int row = t >> 6, dq = t & 63;
        float4 sum = {};
#pragma unroll
        for (int js = 0; js < 8; ++js) {
            float4 pt = *(const float4*)&part[row][js][dq][0];
            sum.x += pt.x; sum.y += pt.y; sum.z += pt.z; sum.w += pt.w;
        }
        *(float4*)(ctx + (size_t)(b * S + i0 + row) * D + (size_t)dq * 4) = sum;
    }
}

extern "C" void kernel_launch(void* const* d_in, const int* in_sizes, int n_in,
                              void* d_out, int out_size, void* d_ws, size_t ws_size,
                              hipStream_t stream) {
    const float* q = (const float*)d_in[0];
    // d_in[1] = key (unused by the reference)
    const float* value = (const float*)d_in[2];
    const float* W = (const float*)d_in[3];
    const float* vm = (const float*)d_in[4];

    float* ctx = (float*)d_out;                    // [B,S,D]
    float* att = ctx + (size_t)B * S * D;          // [B,S,S]
    float* EJ4 = (float*)d_ws;                     // [B][64][S][4] exp2(Pt), 1 MB
    float* EN = EJ4 + (size_t)B * D * S;           // [B,S,D] exp2(-Pt), 1 MB
    float* W2 = EN + (size_t)B * S * D;            // [D] -2*vm, 1 KB

    proj_kernel<<<B * (S / 4), 256, 0, stream>>>(q, W, vm, EJ4, EN, W2);
    fused2x_kernel<<<B * (S / 2), 512, 0, stream>>>(EJ4, EN, W2, value, att, ctx);
}